// Round 15
// baseline (52.414 us; speedup 1.0000x reference)
//
#include <hip/hip_runtime.h>
#include <hip/hip_bf16.h>

// LCN: B=512, C=1, H=W=280, K=S=28, F=10, SPAN=100 (10x10), DEC_IN=1000, OUT=10
// ROUND 15: TWO dispatches. conv = R12's rooflined 1280-block loop with
// B-frags loaded DIRECTLY from fp32 cw + in-register bf16 cvt (wprep gone);
// dec2 = fused combine+bias+relu+decoder+yred -> y (dw/cb staged in LDS).
// R14's cross-XCD atomic tail abandoned (stale P reads across XCDs).
#define HW      280
#define IMG     78400        // 280*280
#define KK      28
#define F_N     10
#define SPAN    100
#define OUT_N   10
#define P_PLANE 512000       // 1000*512

typedef short s16x8 __attribute__((ext_vector_type(8)));   // 8 bf16 (4 VGPRs)
typedef float f32x4 __attribute__((ext_vector_type(4)));   // MFMA C/D

static __device__ __forceinline__ unsigned bits2(__hip_bfloat162 h) {
  return *reinterpret_cast<unsigned*>(&h);
}

// Raw barrier: LDS visibility only (lgkmcnt), NO vmcnt drain -- global loads
// stay in flight across the barrier (bypasses __syncthreads' vmcnt(0) drain).
#define RAW_BARRIER() asm volatile("s_waitcnt lgkmcnt(0)\ns_barrier" ::: "memory")

// Conv via MFMA: grid 1280 = bg(32: 16 b) x hs(10) x rq(4: 7 rows).
// Main loop structure identical to the rooflined R12 kernel (~25us, 6.5TB/s).
// B-frag: 8 fp32 from cw (32B/lane, L2-hot XCD-pinned slice) -> cvt_pk bf16.
// Clamps: f>=10 -> f=0 (D cols 10..15 discarded); dummy ws 10/11 -> ws 0
// (never MFMA'd); kg==3 second half reloads k24..27 (A zeros at k28..31 kill
// any B garbage there) -- all reads in-bounds, results bit-identical to wprep.
__global__ __launch_bounds__(256, 4) void lcn_conv(
    const float* __restrict__ x, const float* __restrict__ cw,
    float* __restrict__ P) {
  const int bid  = blockIdx.x;       // 0..1279
  const int xcd  = bid & 7;
  const int grp  = bid >> 3;         // 0..159
  const int hsrq = xcd + 8 * (grp % 5);  // 0..39, fixed per XCD set
  const int bg   = grp / 5;          // 0..31
  const int hs   = hsrq >> 2;
  const int rq   = hsrq & 3;

  const int tid  = (int)threadIdx.x;
  const int lane = tid & 63;
  const int wid  = tid >> 6;
  const int l15  = lane & 15;
  const int kg   = lane >> 4;        // 0..3

  __shared__ short xl[2][16 * 320];  // 20.5 KB double-buffered A-tile

  // zero the k-pad slots (k 28..31 of each ws), same swizzle as data
  for (int i = tid; i < 2 * 160; i += 256) {
    const int buf = i / 160, j = i - buf * 160;
    const int b = j / 10, ws = j - b * 10;
    const int sidx = (b * 320 + ws * 32 + 28) ^ ((b & 7) << 3);
    *reinterpret_cast<short4*>(&xl[buf][sidx]) = make_short4(0, 0, 0, 0);
  }

  const int nun = (wid < 2) ? 3 : 2;             // ws units per wave (3,3,2,2)
  const int wsl[3] = {wid, wid + 4, wid + 8};    // wsl[2]>=10 for wid 2,3 = dummy

  // clamped, in-bounds w row bases (wave-uniform per unit except l15/kg)
  const int fC = (l15 < F_N) ? l15 : 0;
  const float* wrow[3];
#pragma unroll
  for (int u = 0; u < 3; ++u) {
    const int sC = (wsl[u] < 10) ? (hs * 10 + wsl[u]) : (hs * 10);
    wrow[u] = cw + (size_t)(fC * SPAN + sC) * (KK * KK) + kg * 8;
  }
  const int kOff2 = (kg == 3) ? 0 : 4;           // kg==3: reload k24..27 (safe)

  f32x4 acc[3];
#pragma unroll
  for (int u = 0; u < 3; ++u) acc[u] = (f32x4){0.f, 0.f, 0.f, 0.f};

  const int row0 = hs * KK + rq * 7;
  const float* xbase = x + (size_t)bg * 16 * IMG + (size_t)row0 * HW;

  float4 stgA[5], stgB[5];

#define ISSUE(STG, R)                                                       \
  _Pragma("unroll")                                                         \
  for (int j = 0; j < 5; ++j) {                                             \
    const int i = tid + 256 * j;                                            \
    if (i < 1120) {                                                         \
      const int b = i / 70, q = i - b * 70;                                 \
      STG[j] = *reinterpret_cast<const float4*>(                            \
          xbase + (size_t)b * IMG + (size_t)(R) * HW + q * 4);              \
    }                                                                       \
  }

#define COMMIT(STG, BUF)                                                    \
  _Pragma("unroll")                                                         \
  for (int j = 0; j < 5; ++j) {                                             \
    const int i = tid + 256 * j;                                            \
    if (i < 1120) {                                                         \
      const int b = i / 70, q = i - b * 70;                                 \
      const int ws = q / 7, c4 = q - ws * 7;                                \
      const int sidx = (b * 320 + ws * 32 + c4 * 4) ^ ((b & 7) << 3);       \
      uint2 pk;                                                             \
      pk.x = bits2(__float22bfloat162_rn(make_float2(STG[j].x, STG[j].y))); \
      pk.y = bits2(__float22bfloat162_rn(make_float2(STG[j].z, STG[j].w))); \
      *reinterpret_cast<uint2*>(&xl[BUF][sidx]) = pk;                       \
    }                                                                       \
  }

// B-frag load (fp32 -> bf16 in-reg). Issued FIRST in each phase (oldest vmem)
// so the MFMA's wait leaves the x prefetch below outstanding.
#define BLOAD(BFR, RR)                                                      \
  _Pragma("unroll")                                                         \
  for (int u = 0; u < 3; ++u) {                                             \
    const float* wp = wrow[u] + (RR) * KK;                                  \
    const float4 w0 = *reinterpret_cast<const float4*>(wp);                 \
    const float4 w1 = *reinterpret_cast<const float4*>(wp + kOff2);         \
    union { unsigned q[4]; s16x8 v; } pk_;                                  \
    pk_.q[0] = bits2(__float22bfloat162_rn(make_float2(w0.x, w0.y)));       \
    pk_.q[1] = bits2(__float22bfloat162_rn(make_float2(w0.z, w0.w)));       \
    pk_.q[2] = bits2(__float22bfloat162_rn(make_float2(w1.x, w1.y)));       \
    pk_.q[3] = bits2(__float22bfloat162_rn(make_float2(w1.z, w1.w)));       \
    BFR[u] = pk_.v;                                                         \
  }

  // prologue: rows 0 (A) and 1 (B) in flight; commit A; lgkm barrier
  ISSUE(stgA, 0)
  ISSUE(stgB, 1)
  COMMIT(stgA, 0)            // waits A's loads only (B stays in flight)
  RAW_BARRIER();

#pragma unroll
  for (int r = 0; r < 7; ++r) {
    const int buf = r & 1;
    const int rr  = rq * 7 + r;

    // (1) B-frags FIRST (oldest vmem this phase)
    s16x8 bfr[3];
    BLOAD(bfr, rr)

    // (2) x prefetch row r+2 (newest vmem; survives MFMA wait + raw barrier)
    if (r + 2 < 7) {
      if (r & 1) { ISSUE(stgB, r + 2) } else { ISSUE(stgA, r + 2) }
    }

    // (3) MFMA row r from xl[buf]
#pragma unroll
    for (int u = 0; u < 3; ++u) {
      if (u < nun) {
        const int ws = wsl[u];
        const int sidx = (l15 * 320 + ws * 32 + kg * 8) ^ ((l15 & 7) << 3);
        const s16x8 afr = *reinterpret_cast<const s16x8*>(&xl[buf][sidx]);
        acc[u] = __builtin_amdgcn_mfma_f32_16x16x32_bf16(afr, bfr[u], acc[u], 0, 0, 0);
      }
    }

    // (4) commit row r+1 (issued last phase) into buf^1; lgkm-only barrier
    if (r < 6) {
      if (r & 1) { COMMIT(stgA, buf ^ 1) } else { COMMIT(stgB, buf ^ 1) }
      RAW_BARRIER();
    }
  }

  // D layout: row(b-off) = kg*4+j, col(f) = l15. P[rq][f*100+s][b].
  if (l15 < F_N) {
#pragma unroll
    for (int u = 0; u < 3; ++u) {
      if (u < nun) {
        const int s = hs * 10 + wsl[u];
        float* Pp = P + (size_t)rq * P_PLANE + (size_t)(l15 * SPAN + s) * 512
                      + bg * 16 + kg * 4;
        *reinterpret_cast<float4*>(Pp) =
            make_float4(acc[u][0], acc[u][1], acc[u][2], acc[u][3]);
      }
    }
  }
}

// dec2: combine 4 rq planes + bias + relu + full decoder + db -> y.
// grid 32 blocks (16 b each) x 512 threads = (b16, dway 0..31); dw (40KB) and
// cb (4KB) staged in LDS (16-lane-uniform broadcast reads); LDS-reduce 32
// dways; 160 threads write y. Replaces dec + yred (one dispatch + gap saved).
__global__ __launch_bounds__(512) void lcn_dec2(
    const float* __restrict__ P, const float* __restrict__ cb,
    const float* __restrict__ dw, const float* __restrict__ db,
    float* __restrict__ y) {
  const int tid  = (int)threadIdx.x;
  const int b16  = tid & 15;
  const int dway = tid >> 4;             // 0..31
  const int b    = blockIdx.x * 16 + b16;

  __shared__ float dwl[OUT_N * 1000];    // 40 KB [o][d]
  __shared__ float cbl[1000];            // 4 KB
  for (int i = tid; i < OUT_N * 1000; i += 512) dwl[i] = dw[i];
  for (int i = tid; i < 1000; i += 512) cbl[i] = cb[i];
  __syncthreads();

  float acc[OUT_N];
#pragma unroll
  for (int o = 0; o < OUT_N; ++o) acc[o] = 0.f;

#pragma unroll 4
  for (int k = 0; k < 32; ++k) {
    const int d = dway + 32 * k;
    if (d < 1000) {
      const float* pd = P + (size_t)d * 512 + b;   // coalesced over 16 lanes
      const float p = pd[0] + pd[P_PLANE] + pd[2 * (size_t)P_PLANE]
                            + pd[3 * (size_t)P_PLANE];
      const float h = fmaxf(p + cbl[d], 0.f);
#pragma unroll
      for (int o = 0; o < OUT_N; ++o)
        acc[o] = fmaf(h, dwl[o * 1000 + d], acc[o]);
    }
  }

  __shared__ float red[32][OUT_N][16];   // 20.5 KB
#pragma unroll
  for (int o = 0; o < OUT_N; ++o) red[dway][o][b16] = acc[o];
  __syncthreads();

  if (tid < 16 * OUT_N) {
    const int bb = tid & 15, o = tid >> 4;
    float a = db[o];
#pragma unroll
    for (int w2 = 0; w2 < 32; ++w2) a += red[w2][o][bb];
    y[(blockIdx.x * 16 + bb) * OUT_N + o] = a;
  }
}

extern "C" void kernel_launch(void* const* d_in, const int* in_sizes, int n_in,
                              void* d_out, int out_size, void* d_ws, size_t ws_size,
                              hipStream_t stream) {
  const float* x  = (const float*)d_in[0];   // [512,1,280,280]
  const float* cw = (const float*)d_in[1];   // [1000,1,28,28]
  const float* cb = (const float*)d_in[2];   // [1000,1]
  const float* dw = (const float*)d_in[3];   // [10,1000]
  const float* db = (const float*)d_in[4];   // [10]
  float* y = (float*)d_out;                  // [512,10]

  float* P = (float*)d_ws;                   // [4][1000][512] = 8.192 MB

  lcn_conv<<<dim3(1280), dim3(256), 0, stream>>>(x, cw, P);
  lcn_dec2<<<dim3(32),   dim3(512), 0, stream>>>(P, cb, dw, db, y);
}

// Round 16
// 40.072 us; speedup vs baseline: 1.3080x; 1.3080x over previous
//
#include <hip/hip_runtime.h>
#include <hip/hip_bf16.h>

// LCN: B=512, C=1, H=W=280, K=S=28, F=10, SPAN=100 (10x10), DEC_IN=1000, OUT=10
// ROUND 16: TWO dispatches.
//  1) wprep: w -> bf16 MFMA layout (R13's, measured-good) + y := db broadcast.
//  2) conv320 fused (R13's passing kernel: 28 rows in accumulators, fused
//     bias+relu+decoder) with atomicAdd of per-hs decoder partials into y
//     (device-scope atomics = the sanctioned cross-XCD combine; R14's
//     plain-store+fence handoff was the broken variant).
#define HW      280
#define IMG     78400        // 280*280
#define KK      28
#define F_N     10
#define SPAN    100
#define OUT_N   10

typedef short s16x8 __attribute__((ext_vector_type(8)));   // 8 bf16 (4 VGPRs)
typedef float f32x4 __attribute__((ext_vector_type(4)));   // MFMA C/D

static __device__ __forceinline__ unsigned bits2(__hip_bfloat162 h) {
  return *reinterpret_cast<unsigned*>(&h);
}

// Raw barrier: LDS visibility only (lgkmcnt), NO vmcnt drain -- global loads
// stay in flight across the barrier (bypasses __syncthreads' vmcnt(0) drain).
#define RAW_BARRIER() asm volatile("s_waitcnt lgkmcnt(0)\ns_barrier" ::: "memory")

// wprep: wbuf[s][r][f 16][k 32] bf16 (k 28..31 zero; f 10..15 unwritten).
// Thread = one (f,s,r) row: src = cw + idx*28 is PERFECTLY LINEAR.
// Blocks 0..19 also initialize y[b][o] = db[o] (conv then atomicAdds into it;
// stream order makes the init visible before conv).
__global__ __launch_bounds__(256) void wprep(const float* __restrict__ cw,
                                             uint4* __restrict__ wbuf4,
                                             const float* __restrict__ db,
                                             float* __restrict__ y) {
  const int idx = blockIdx.x * 256 + (int)threadIdx.x;  // 0..28159
  if (idx < 5120) y[idx] = db[idx % OUT_N];             // y init
  if (idx >= 28000) return;
  const int fs = idx / 28;          // f*100 + s
  const int r  = idx - fs * 28;
  const int f  = fs / 100;
  const int s  = fs - f * 100;

  const float* src = cw + (size_t)idx * 28;   // 112B, 16B-aligned
  float v[28];
#pragma unroll
  for (int j = 0; j < 7; ++j)
    *reinterpret_cast<float4*>(&v[j * 4]) =
        *reinterpret_cast<const float4*>(src + j * 4);

  unsigned p[16];
#pragma unroll
  for (int k2 = 0; k2 < 14; ++k2)
    p[k2] = bits2(__float22bfloat162_rn(make_float2(v[2 * k2], v[2 * k2 + 1])));
  p[14] = 0u; p[15] = 0u;

  uint4* dst = wbuf4 + ((size_t)(s * 28 + r) * 16 + f) * 4;  // 64B aligned
  dst[0] = make_uint4(p[0],  p[1],  p[2],  p[3]);
  dst[1] = make_uint4(p[4],  p[5],  p[6],  p[7]);
  dst[2] = make_uint4(p[8],  p[9],  p[10], p[11]);
  dst[3] = make_uint4(p[12], p[13], p[14], p[15]);
}

// Fused conv+bias+relu+decoder. grid 320 = bg(32: 16 b) x hs(10).
// Main loop byte-identical to R13's passing kernel (28 rows, raw lgkm
// barriers, B-frags oldest, x prefetch depth 2, K=784 in accumulators).
// Epilogue: D-frags -> h_lds[100 d][16 b]; 160 threads dot the decoder and
// atomicAdd per-hs partials into y (device-scope, cross-XCD safe).
__global__ __launch_bounds__(256, 4) void lcn_conv(
    const float* __restrict__ x, const unsigned short* __restrict__ wbuf,
    const float* __restrict__ cb, const float* __restrict__ dw,
    float* __restrict__ y) {
  const int bid = blockIdx.x;        // 0..319
  const int hs  = bid % 10;
  const int bg  = bid / 10;          // 0..31

  const int tid  = (int)threadIdx.x;
  const int lane = tid & 63;
  const int wid  = tid >> 6;
  const int l15  = lane & 15;
  const int kg   = lane >> 4;        // 0..3

  __shared__ short xl[2][16 * 320];  // 20.5 KB double-buffered A-tile
  __shared__ float h_lds[100 * 16];  // relu'd conv out [d_local=f*10+ws][b16]
  __shared__ float dw_lds[1000];     // dw slice [o][f*10+ws] for this hs

  // stage dw slice (visibility covered by the prologue barrier + final sync)
  for (int i = tid; i < 1000; i += 256) {
    const int o  = i / 100, dl = i - o * 100;
    const int f  = dl / 10, ws = dl - f * 10;
    dw_lds[i] = dw[o * 1000 + f * 100 + hs * 10 + ws];
  }

  // zero the k-pad slots (k 28..31 of each ws), same swizzle as data
  for (int i = tid; i < 2 * 160; i += 256) {
    const int buf = i / 160, j = i - buf * 160;
    const int b = j / 10, ws = j - b * 10;
    const int sidx = (b * 320 + ws * 32 + 28) ^ ((b & 7) << 3);
    *reinterpret_cast<short4*>(&xl[buf][sidx]) = make_short4(0, 0, 0, 0);
  }

  const int nun = (wid < 2) ? 3 : 2;             // ws units per wave (3,3,2,2)
  const int wsl[3] = {wid, wid + 4, wid + 8};    // ws 10/11 hit pad s-slots, never MFMA'd

  f32x4 acc[3];
#pragma unroll
  for (int u = 0; u < 3; ++u) acc[u] = (f32x4){0.f, 0.f, 0.f, 0.f};

  const float* xbase = x + (size_t)bg * 16 * IMG + (size_t)(hs * KK) * HW;

  float4 stgA[5], stgB[5];

#define ISSUE(STG, R)                                                       \
  _Pragma("unroll")                                                         \
  for (int j = 0; j < 5; ++j) {                                             \
    const int i = tid + 256 * j;                                            \
    if (i < 1120) {                                                         \
      const int b = i / 70, q = i - b * 70;                                 \
      STG[j] = *reinterpret_cast<const float4*>(                            \
          xbase + (size_t)b * IMG + (size_t)(R) * HW + q * 4);              \
    }                                                                       \
  }

#define COMMIT(STG, BUF)                                                    \
  _Pragma("unroll")                                                         \
  for (int j = 0; j < 5; ++j) {                                             \
    const int i = tid + 256 * j;                                            \
    if (i < 1120) {                                                         \
      const int b = i / 70, q = i - b * 70;                                 \
      const int ws = q / 7, c4 = q - ws * 7;                                \
      const int sidx = (b * 320 + ws * 32 + c4 * 4) ^ ((b & 7) << 3);       \
      uint2 pk;                                                             \
      pk.x = bits2(__float22bfloat162_rn(make_float2(STG[j].x, STG[j].y))); \
      pk.y = bits2(__float22bfloat162_rn(make_float2(STG[j].z, STG[j].w))); \
      *reinterpret_cast<uint2*>(&xl[BUF][sidx]) = pk;                       \
    }                                                                       \
  }

#define BLOAD(BFR, RR)                                                      \
  _Pragma("unroll")                                                         \
  for (int u = 0; u < 3; ++u)                                               \
    BFR[u] = *reinterpret_cast<const s16x8*>(                               \
        wbuf + (size_t)((hs * 10 + wsl[u]) * 28 + (RR)) * 512 + l15 * 32 + kg * 8);

#define MFMAS(BFR, BUF)                                                     \
  _Pragma("unroll")                                                         \
  for (int u = 0; u < 3; ++u) {                                             \
    if (u < nun) {                                                          \
      const int sidx = (l15 * 320 + wsl[u] * 32 + kg * 8) ^ ((l15 & 7) << 3); \
      const s16x8 afr = *reinterpret_cast<const s16x8*>(&xl[BUF][sidx]);    \
      acc[u] = __builtin_amdgcn_mfma_f32_16x16x32_bf16(afr, BFR[u], acc[u], 0, 0, 0); \
    }                                                                       \
  }

  // prologue: rows 0 (A) and 1 (B) in flight; commit A; lgkm barrier
  ISSUE(stgA, 0)
  ISSUE(stgB, 1)
  COMMIT(stgA, 0)            // waits A's loads only (B stays in flight)
  RAW_BARRIER();

#pragma unroll 1
  for (int r2 = 0; r2 < 14; ++r2) {
    const int re = 2 * r2;
    // ---- even phase: compute row re from xl[0] ----
    s16x8 bfrE[3];
    BLOAD(bfrE, re)
    if (re + 2 < 28) { ISSUE(stgA, re + 2) }     // newest vmem, stays in flight
    MFMAS(bfrE, 0)
    COMMIT(stgB, 1)                              // row re+1 -> buf 1
    RAW_BARRIER();
    // ---- odd phase: compute row re+1 from xl[1] ----
    const int ro = re + 1;
    s16x8 bfrO[3];
    BLOAD(bfrO, ro)
    if (ro + 2 < 28) { ISSUE(stgB, ro + 2) }
    MFMAS(bfrO, 1)
    if (r2 < 13) {
      COMMIT(stgA, 0)                            // row ro+1 -> buf 0
      RAW_BARRIER();
    }
  }

  // ---- fused epilogue ----
  // D layout: row(b-off) = kg*4+j, col(f) = l15.
  if (l15 < F_N) {
#pragma unroll
    for (int u = 0; u < 3; ++u) {
      if (u < nun) {
        const int ws = wsl[u];
        const float bias = cb[l15 * 100 + hs * 10 + ws];
        float4 hv;
        hv.x = fmaxf(acc[u][0] + bias, 0.f);
        hv.y = fmaxf(acc[u][1] + bias, 0.f);
        hv.z = fmaxf(acc[u][2] + bias, 0.f);
        hv.w = fmaxf(acc[u][3] + bias, 0.f);
        *reinterpret_cast<float4*>(&h_lds[(l15 * 10 + ws) * 16 + kg * 4]) = hv;
      }
    }
  }
  __syncthreads();

  // decoder: thread (b16, o) dots 100 d's from LDS (broadcast reads), then
  // device-scope atomicAdd of this hs-partial into y[b][o] (init'd to db).
  if (tid < 16 * OUT_N) {
    const int b16 = tid & 15;
    const int o   = tid >> 4;
    float a = 0.f;
#pragma unroll 10
    for (int dl = 0; dl < 100; ++dl)
      a = fmaf(h_lds[dl * 16 + b16], dw_lds[o * 100 + dl], a);
    atomicAdd(&y[(bg * 16 + b16) * OUT_N + o], a);
  }
}

extern "C" void kernel_launch(void* const* d_in, const int* in_sizes, int n_in,
                              void* d_out, int out_size, void* d_ws, size_t ws_size,
                              hipStream_t stream) {
  const float* x  = (const float*)d_in[0];   // [512,1,280,280]
  const float* cw = (const float*)d_in[1];   // [1000,1,28,28]
  const float* cb = (const float*)d_in[2];   // [1000,1]
  const float* dw = (const float*)d_in[3];   // [10,1000]
  const float* db = (const float*)d_in[4];   // [10]
  float* y = (float*)d_out;                  // [512,10]

  uint4* wbuf = (uint4*)d_ws;                // [102][28][16][16]u32 = 2.92 MB

  wprep   <<<dim3(110), dim3(256), 0, stream>>>(cw, wbuf, db, y);
  lcn_conv<<<dim3(320), dim3(256), 0, stream>>>(x, (const unsigned short*)wbuf,
                                                cb, dw, y);
}